// Round 11
// baseline (203.499 us; speedup 1.0000x reference)
//
#include <hip/hip_runtime.h>
#include <hip/hip_bf16.h>
#include <cstdint>
#include <cstddef>

// Problem constants
#define B_N 8192
#define D_K 1024
#define H_N 400
#define HP  416          // H padded to multiple of 32
#define K2_N 512
#define E_N 16
#define L_N 256
#define TM 64
#define PAD_ROWS (B_N + E_N * TM)   // 9216
#define NTILES (PAD_ROWS / TM)      // 144

typedef short bf16x8 __attribute__((ext_vector_type(8)));
typedef float f32x4 __attribute__((ext_vector_type(4)));

// async global->LDS, 16B per lane; LDS dest = wave-uniform base + lane*16.
// Global address may be fully per-lane (gather OK).
#define GLDS(gp, lp) __builtin_amdgcn_global_load_lds( \
    (const __attribute__((address_space(1))) unsigned int*)(gp), \
    (__attribute__((address_space(3))) unsigned int*)(lp), 16, 0, 0)

static __device__ __forceinline__ unsigned short f2bf(float f) {
  union { float f; unsigned int u; } c; c.f = f;
  unsigned int u = c.u + 0x7fffu + ((c.u >> 16) & 1u);  // RNE
  return (unsigned short)(u >> 16);
}
static __device__ __forceinline__ unsigned int pkbf(float a, float b) {
  union { __hip_bfloat162 v; unsigned int u; } c;
  c.v = __float22bfloat162_rn(make_float2(a, b));
  return c.u;
}

// ---------------- prep (one launch, fully parallel blocks): ----------------
// Round-10: x-convert pass REMOVED (gemm1 now reg-stages f32 x directly).
// Unit order (longest-first, round-9 win):
// [0,32):      scatter: block hb places samples [hb*256,hb*256+256).
//              Per-wave sub-histograms (4x16, waves don't contend) +
//              wave-uniform chunk test c<hb. hb==0 publishes off_al/cnt_al.
// [32,1824):   W1 transpose [1024][400] f32 -> [416][1024] bf16 (zero-pad)
// [1824,2720): W2 transpose [400][512] f32 -> [512][416] bf16 (zero-pad)
__global__ __launch_bounds__(256) void prep_kernel(const float* __restrict__ W1,
                                                   const float* __restrict__ W2,
                                                   const int* __restrict__ idx,
                                                   unsigned short* __restrict__ Wt1,
                                                   unsigned short* __restrict__ Wt2,
                                                   int* __restrict__ off_al,
                                                   int* __restrict__ cnt_al,
                                                   int* __restrict__ order) {
  const int bid = blockIdx.x;
  const int t = threadIdx.x;
  if (bid < 32) {
    const int hb = bid;
    __shared__ int totW[4][E_N], preW[4][E_N];
    __shared__ int totL[E_N], preL[E_N], offsL[E_N], curL[E_N];
    const int wv = t >> 6;
    if (t < 64) { totW[t >> 4][t & 15] = 0; preW[t >> 4][t & 15] = 0; }
    __syncthreads();
#pragma unroll 1
    for (int c = 0; c < 32; ++c) {
      const int e0 = idx[c * 256 + t];
      atomicAdd(&totW[wv][e0], 1);
      if (c < hb) atomicAdd(&preW[wv][e0], 1);   // wave-uniform branch
    }
    __syncthreads();
    if (t < E_N) {
      totL[t] = totW[0][t] + totW[1][t] + totW[2][t] + totW[3][t];
      preL[t] = preW[0][t] + preW[1][t] + preW[2][t] + preW[3][t];
    }
    __syncthreads();
    if (t == 0) {
      int acc = 0;
      for (int e = 0; e < E_N; ++e) {
        offsL[e] = acc;
        if (hb == 0) off_al[e] = acc;
        acc += ((totL[e] + TM - 1) / TM) * TM;
      }
      if (hb == 0) off_al[E_N] = acc;
    }
    __syncthreads();
    if (t < E_N) {
      curL[t] = offsL[t] + preL[t];
      if (hb == 0) cnt_al[t] = totL[t];
    }
    __syncthreads();
    const int b = hb * 256 + t;
    const int e = idx[b];
    const int slot = atomicAdd(&curL[e], 1);
    order[slot] = b;
  } else {
    const int u = bid - 32;
    __shared__ unsigned short Ls[64][72];
    const float* S; unsigned short* Dt; int K, N, Kd, Nd, k0, n0;
    if (u < 1792) {                      // W1: 16 k-blocks x 7 n-blocks x 16 e
      int e = u / 112, r = u % 112;
      k0 = (r % 16) * 64; n0 = (r / 16) * 64;
      S = W1 + (size_t)e * D_K * H_N; Dt = Wt1 + (size_t)e * HP * D_K;
      K = D_K; N = H_N; Kd = D_K; Nd = HP;
    } else {                             // W2: 7 k-blocks x 8 n-blocks x 16 e
      int t2 = u - 1792; int e = t2 / 56, r = t2 % 56;
      k0 = (r % 7) * 64; n0 = (r / 7) * 64;
      S = W2 + (size_t)e * H_N * K2_N; Dt = Wt2 + (size_t)e * K2_N * HP;
      K = H_N; N = K2_N; Kd = HP; Nd = K2_N;
    }
    const int kk = t >> 4;
    const int nn = (t & 15) * 4;
    float4 v[4];
#pragma unroll
    for (int p = 0; p < 4; ++p) {
      int k = k0 + p * 16 + kk;
      int n = n0 + nn;
      v[p] = make_float4(0.f, 0.f, 0.f, 0.f);
      if (k < K && n + 3 < N) v[p] = *(const float4*)(S + (size_t)k * N + n);
    }
#pragma unroll
    for (int p = 0; p < 4; ++p) {
      Ls[nn + 0][p * 16 + kk] = f2bf(v[p].x);
      Ls[nn + 1][p * 16 + kk] = f2bf(v[p].y);
      Ls[nn + 2][p * 16 + kk] = f2bf(v[p].z);
      Ls[nn + 3][p * 16 + kk] = f2bf(v[p].w);
    }
    __syncthreads();
    const int n2 = t >> 3;
    const int ch = t & 7;
#pragma unroll
    for (int p = 0; p < 2; ++p) {
      int n = n0 + p * 32 + n2;
      int k = k0 + ch * 8;
      if (n < Nd && k < Kd)
        *(uint4*)(Dt + (size_t)n * Kd + k) = *(const uint4*)&Ls[p * 32 + n2][ch * 8];
    }
  }
}

// XCD-clustering swizzle for the GEMM grids (576 wgs, 8 XCDs, 72/XCD):
// linear dispatch id L -> vid = (L%8)*72 + L/8 (bijective), decode
// mt = vid>>2 (m-tile), nb = vid&3 (n-chunk).
static __device__ __forceinline__ void swz_decode(int bx, int by, int& mt, int& nb) {
  const int L = bx + NTILES * by;          // 0..575
  const int vid = (L & 7) * 72 + (L >> 3);
  mt = vid >> 2;
  nb = vid & 3;
}

// ---------------- GEMM1: A reg-staged from f32 x (xc pass eliminated) -------
// grid (144,4) swizzled; two 16-col tiles/wave; BK=64 of two 32-wide swizzled
// sub-tiles (16 iters). A: lane loads 2x float4 of x row rowidx[16w+r4] at
// chunk ((l&3)^sg)*8 (same XOR mapping GLDS used), cvt->ds_write_b128 to the
// SAME As bytes as before. 2-deep reg pipeline, static parity (unroll-2):
// chunk i+2's loads issued one iteration before their ds_write. Pad rows ->
// zero regs. B staging / MFMA / epilogue byte-exact R2 config.
__global__ __launch_bounds__(256) void gemm1_kernel(const float* __restrict__ x,
                                                    const unsigned short* __restrict__ Wt1,
                                                    const float* __restrict__ b1,
                                                    const int* __restrict__ off_al,
                                                    const int* __restrict__ cnt_al,
                                                    const int* __restrict__ order,
                                                    unsigned short* __restrict__ h1buf) {
  __shared__ unsigned short As[2 * 2 * 2048];   // [buf][ksub][64*32]  16 KB
  __shared__ unsigned short Bs[2 * 2 * 4096];   // [buf][ksub][128*32] 32 KB
  __shared__ int offs[E_N + 1];
  __shared__ int rowidx[TM];
  const int tid = threadIdx.x;
  int mt, nb;
  swz_decode(blockIdx.x, blockIdx.y, mt, nb);
  const int m0 = mt * TM;
  if (tid <= E_N) offs[tid] = off_al[tid];
  __syncthreads();
  if (m0 >= offs[E_N]) return;
  int e = 0;
  while (m0 >= offs[e + 1]) ++e;
  if (tid < TM) {
    const bool valid = (m0 + tid) < (offs[e] + cnt_al[e]);
    rowidx[tid] = valid ? order[m0 + tid] : -1;   // pad -> -1 (zero A row)
  }
  __syncthreads();
  const unsigned short* Wt1e = Wt1 + (size_t)e * HP * D_K;

  const int l = tid & 63, w = tid >> 6;
  const int r4 = l >> 2;
  const int sg = (r4 ^ (r4 >> 2)) & 3;
  const int c8 = ((l & 3) ^ sg) * 8;        // source chunk (elements)
  const int t0 = nb * 8 + 2 * w;            // first of two 16-col tiles (0..24)
  const bool act0 = (t0 < 25);
  const bool act1 = (t0 + 1 < 25);
  const int ar = rowidx[16 * w + r4];
  const bool av = (ar >= 0);
  const float* gAx = x + (size_t)(av ? ar : 0) * D_K + c8;
  const unsigned short* gB0 = Wt1e + (size_t)(t0 * 16 + r4) * D_K + c8;
  const unsigned short* gB1 = gB0 + (size_t)16 * D_K;

  const int ln = l & 15, q = l >> 4;
  const int sr = (ln ^ (ln >> 2)) & 3;
  const int cq = (q ^ sr) * 8;

  f32x4 acc[4][2] = {};
  const float4 fz = make_float4(0.f, 0.f, 0.f, 0.f);
  const int awoff = 16 * w * 32 + r4 * 32 + (l & 3) * 8;   // lane's As slot (shorts)

  // --- A reg pipeline: two static parities (p0 even chunks, p1 odd) ---------
  float4 Alo0[2], Ahi0[2], Alo1[2], Ahi1[2];
#define ALOAD(P, CH)                                                      \
  do { _Pragma("unroll")                                                  \
    for (int ks = 0; ks < 2; ++ks) {                                      \
      const float* s_ = gAx + (CH) * 64 + ks * 32;                        \
      Alo##P[ks] = av ? *(const float4*)s_ : fz;                          \
      Ahi##P[ks] = av ? *(const float4*)(s_ + 4) : fz;                    \
    } } while (0)
#define AWRITE(P, BUF)                                                    \
  do { _Pragma("unroll")                                                  \
    for (int ks = 0; ks < 2; ++ks) {                                      \
      uint4 o_;                                                           \
      o_.x = pkbf(Alo##P[ks].x, Alo##P[ks].y);                            \
      o_.y = pkbf(Alo##P[ks].z, Alo##P[ks].w);                            \
      o_.z = pkbf(Ahi##P[ks].x, Ahi##P[ks].y);                            \
      o_.w = pkbf(Ahi##P[ks].z, Ahi##P[ks].w);                            \
      *(uint4*)&As[(BUF) * 4096 + ks * 2048 + awoff] = o_;                \
    } } while (0)

  auto stageB = [&](int chunk, int buf) {
#pragma unroll
    for (int ks = 0; ks < 2; ++ks) {
      const int kg = chunk * 64 + ks * 32;
      if (act0) GLDS(gB0 + kg, &Bs[buf * 8192 + ks * 4096 + (2 * w + 0) * 512]);
      if (act1) GLDS(gB1 + kg, &Bs[buf * 8192 + ks * 4096 + (2 * w + 1) * 512]);
    }
  };

  auto mfma = [&](int buf) {
    if (act0) {
#pragma unroll
      for (int ks = 0; ks < 2; ++ks) {
        const unsigned short* Ab = &As[buf * 4096 + ks * 2048];
        const unsigned short* Bb = &Bs[buf * 8192 + ks * 4096];
        bf16x8 af[4];
#pragma unroll
        for (int i = 0; i < 4; ++i)
          af[i] = *(const bf16x8*)&Ab[(16 * i + ln) * 32 + cq];
        bf16x8 b0f = *(const bf16x8*)&Bb[(2 * w + 0) * 512 + ln * 32 + cq];
#pragma unroll
        for (int i = 0; i < 4; ++i)
          acc[i][0] = __builtin_amdgcn_mfma_f32_16x16x32_bf16(b0f, af[i], acc[i][0], 0, 0, 0);
        if (act1) {
          bf16x8 b1f = *(const bf16x8*)&Bb[(2 * w + 1) * 512 + ln * 32 + cq];
#pragma unroll
          for (int i = 0; i < 4; ++i)
            acc[i][1] = __builtin_amdgcn_mfma_f32_16x16x32_bf16(b1f, af[i], acc[i][1], 0, 0, 0);
        }
      }
    }
  };

  // prologue: chunk0 -> regs p0 -> As buf0; B chunk0 -> buf0; chunk1 -> regs p1
  ALOAD(0, 0);
  AWRITE(0, 0);
  stageB(0, 0);
  ALOAD(1, 1);

  // 16 chunks, manual unroll-2 (even: cur=0, odd: cur=1) -> static parities
#pragma unroll 1
  for (int kk = 0; kk < 16; kk += 2) {
    // even iter i=kk: cur=buf0, nxt=buf1
    __syncthreads();               // publishes buf0 (drains vm+lgkm)
    if (kk + 2 < 16) ALOAD(0, kk + 2);     // chunk kk+2 -> parity 0 (in flight)
    if (kk + 1 < 16) { AWRITE(1, 1); stageB(kk + 1, 1); }  // chunk kk+1 -> buf1
    mfma(0);
    // odd iter i=kk+1: cur=buf1, nxt=buf0
    __syncthreads();               // publishes buf1
    if (kk + 3 < 16) ALOAD(1, kk + 3);     // chunk kk+3 -> parity 1
    if (kk + 2 < 16) { AWRITE(0, 0); stageB(kk + 2, 0); }  // chunk kk+2 -> buf0
    mfma(1);
  }
#undef ALOAD
#undef AWRITE

  // swapped layout: lane holds m = m0+16i+ln (col=lane&15), n = tile*16+4q+reg.
#pragma unroll
  for (int j = 0; j < 2; ++j) {
    if (j == 0 ? act0 : act1) {
      const int n4 = (t0 + j) * 16 + 4 * q;          // always < 400
      const float4 bv = *(const float4*)&b1[e * H_N + n4];
#pragma unroll
      for (int i = 0; i < 4; ++i) {
        const size_t m = (size_t)(m0 + 16 * i + ln);
        uint2 o;
        o.x = pkbf(fmaxf(acc[i][j][0] + bv.x, 0.f), fmaxf(acc[i][j][1] + bv.y, 0.f));
        o.y = pkbf(fmaxf(acc[i][j][2] + bv.z, 0.f), fmaxf(acc[i][j][3] + bv.w, 0.f));
        *(uint2*)&h1buf[m * HP + n4] = o;
      }
    }
  }
  // h1 pad cols [400,416) stay unwritten: Wt2 rows there are zero.
}

// ---------------- GEMM2 (byte-exact best-measured R2 config) ----------------
// grid (144,4) swizzled; two 16-col tiles/wave; BK=64 double-sub-tile K-step.
// K=416 -> 7 iterations, last does only the low 32-wide half.
__global__ __launch_bounds__(256) void gemm2_kernel(const unsigned short* __restrict__ h1buf,
                                                    const unsigned short* __restrict__ Wt2,
                                                    const float* __restrict__ b2,
                                                    const int* __restrict__ off_al,
                                                    const int* __restrict__ cnt_al,
                                                    const int* __restrict__ order,
                                                    float* __restrict__ out) {
  __shared__ unsigned short As[2 * 2 * 2048];
  __shared__ unsigned short Bs[2 * 2 * 4096];
  __shared__ int offs[E_N + 1];
  __shared__ int rowidx[TM];
  const int tid = threadIdx.x;
  int mt, nb;
  swz_decode(blockIdx.x, blockIdx.y, mt, nb);
  const int m0 = mt * TM;
  if (tid <= E_N) offs[tid] = off_al[tid];
  __syncthreads();
  if (m0 >= offs[E_N]) return;
  int e = 0;
  while (m0 >= offs[e + 1]) ++e;
  if (tid < TM) {
    const bool valid = (m0 + tid) < (offs[e] + cnt_al[e]);
    rowidx[tid] = valid ? order[m0 + tid] : -1;
  }
  __syncthreads();
  const unsigned short* Wt2e = Wt2 + (size_t)e * K2_N * HP;

  const int l = tid & 63, w = tid >> 6;
  const int r4 = l >> 2;
  const int sg = (r4 ^ (r4 >> 2)) & 3;
  const int g8 = ((l & 3) ^ sg) * 8;
  const int t0 = nb * 8 + 2 * w;            // two 16-col tiles of 32 (exact)
  const unsigned short* gA = h1buf + (size_t)(m0 + 16 * w + r4) * HP + g8;
  const unsigned short* gB0 = Wt2e + (size_t)(t0 * 16 + r4) * HP + g8;
  const unsigned short* gB1 = gB0 + (size_t)16 * HP;

  const int ln = l & 15, q = l >> 4;
  const int sr = (ln ^ (ln >> 2)) & 3;
  const int cq = (q ^ sr) * 8;

  f32x4 acc[4][2] = {};

  // prologue: stage K 0..63 into buf 0
#pragma unroll
  for (int ks = 0; ks < 2; ++ks) {
    GLDS(gA + ks * 32, &As[ks * 2048 + 16 * w * 32]);
    GLDS(gB0 + ks * 32, &Bs[ks * 4096 + (2 * w + 0) * 512]);
    GLDS(gB1 + ks * 32, &Bs[ks * 4096 + (2 * w + 1) * 512]);
  }

  for (int k0 = 0; k0 < HP; k0 += 64) {     // 7 iterations (last = half)
    const int cur = (k0 >> 6) & 1;
    const int nxt = cur ^ 1;
    __syncthreads();
#pragma unroll
    for (int ks = 0; ks < 2; ++ks) {
      const int kg = k0 + 64 + ks * 32;
      if (kg < HP) {
        GLDS(gA + kg, &As[nxt * 4096 + ks * 2048 + 16 * w * 32]);
        GLDS(gB0 + kg, &Bs[nxt * 8192 + ks * 4096 + (2 * w + 0) * 512]);
        GLDS(gB1 + kg, &Bs[nxt * 8192 + ks * 4096 + (2 * w + 1) * 512]);
      }
    }
#pragma unroll
    for (int ks = 0; ks < 2; ++ks) {
      if (k0 + ks * 32 < HP) {
        const unsigned short* Ab = &As[cur * 4096 + ks * 2048];
        const unsigned short* Bb = &Bs[cur * 8192 + ks * 4096];
        bf16x8 af[4];
#pragma unroll
        for (int i = 0; i < 4; ++i)
          af[i] = *(const bf16x8*)&Ab[(16 * i + ln) * 32 + cq];
        bf16x8 b0f = *(const bf16x8*)&Bb[(2 * w + 0) * 512 + ln * 32 + cq];
#pragma unroll
        for (int i = 0; i < 4; ++i)
          acc[i][0] = __builtin_amdgcn_mfma_f32_16x16x32_bf16(b0f, af[i], acc[i][0], 0, 0, 0);
        bf16x8 b1f = *(const bf16x8*)&Bb[(2 * w + 1) * 512 + ln * 32 + cq];
#pragma unroll
        for (int i = 0; i < 4; ++i)
          acc[i][1] = __builtin_amdgcn_mfma_f32_16x16x32_bf16(b1f, af[i], acc[i][1], 0, 0, 0);
      }
    }
  }

  // swapped layout: lane holds m = m0+16i+ln, n = tile*16+4q+reg (4 consecutive).
#pragma unroll
  for (int j = 0; j < 2; ++j) {
    const int n4 = (t0 + j) * 16 + 4 * q;
    const float4 bv = *(const float4*)&b2[e * K2_N + n4];
#pragma unroll
    for (int i = 0; i < 4; ++i) {
      const int s = rowidx[16 * i + ln];
      if (s >= 0) {
        float4 v;
        v.x = acc[i][j][0] + bv.x;
        v.y = acc[i][j][1] + bv.y;
        v.z = acc[i][j][2] + bv.z;
        v.w = acc[i][j][3] + bv.w;
        if (n4 < L_N) *(float4*)&out[(size_t)s * L_N + n4] = v;
        else          *(float4*)&out[(size_t)(B_N + s) * L_N + (n4 - L_N)] = v;
      }
    }
  }
}

extern "C" void kernel_launch(void* const* d_in, const int* in_sizes, int n_in,
                              void* d_out, int out_size, void* d_ws, size_t ws_size,
                              hipStream_t stream) {
  const float* x   = (const float*)d_in[0];
  const int*   idx = (const int*)d_in[1];
  const float* W1  = (const float*)d_in[2];
  const float* b1  = (const float*)d_in[3];
  const float* W2  = (const float*)d_in[4];
  const float* b2  = (const float*)d_in[5];
  float* out = (float*)d_out;

  // ws layout (bytes) — xc slot retired (gemm1 reads x directly):
  // off_al@0 (68) | cnt_al@128 (64) | order@2240 (36864)
  // h1@16,818,368 (9216x416x2) | Wt1@24,486,080 (16x416x1024x2)
  // Wt2@38,117,568 (16x512x416x2)
  char* ws = (char*)d_ws;
  int* off_al = (int*)(ws + 0);
  int* cnt_al = (int*)(ws + 128);
  int* order  = (int*)(ws + 2240);
  unsigned short* h1  = (unsigned short*)(ws + 16818368);
  unsigned short* Wt1 = (unsigned short*)(ws + 24486080);
  unsigned short* Wt2 = (unsigned short*)(ws + 38117568);

  prep_kernel<<<2720, 256, 0, stream>>>(W1, W2, idx, Wt1, Wt2,
                                        off_al, cnt_al, order);
  gemm1_kernel<<<dim3(NTILES, 4), 256, 0, stream>>>(x, Wt1, b1, off_al, cnt_al, order, h1);
  gemm2_kernel<<<dim3(NTILES, 4), 256, 0, stream>>>(h1, Wt2, b2, off_al, cnt_al, order, out);
}

// Round 12
// 156.496 us; speedup vs baseline: 1.3003x; 1.3003x over previous
//
#include <hip/hip_runtime.h>
#include <hip/hip_bf16.h>
#include <cstdint>
#include <cstddef>

// Problem constants
#define B_N 8192
#define D_K 1024
#define H_N 400
#define HP  416          // H padded to multiple of 32
#define K2_N 512
#define E_N 16
#define L_N 256
#define TM 64
#define PAD_ROWS (B_N + E_N * TM)   // 9216
#define NTILES (PAD_ROWS / TM)      // 144

typedef short bf16x8 __attribute__((ext_vector_type(8)));
typedef float f32x4 __attribute__((ext_vector_type(4)));

// async global->LDS, 16B per lane; LDS dest = wave-uniform base + lane*16.
// Global address may be fully per-lane (gather OK).
#define GLDS(gp, lp) __builtin_amdgcn_global_load_lds( \
    (const __attribute__((address_space(1))) unsigned int*)(gp), \
    (__attribute__((address_space(3))) unsigned int*)(lp), 16, 0, 0)

static __device__ __forceinline__ unsigned short f2bf(float f) {
  union { float f; unsigned int u; } c; c.f = f;
  unsigned int u = c.u + 0x7fffu + ((c.u >> 16) & 1u);  // RNE
  return (unsigned short)(u >> 16);
}
static __device__ __forceinline__ unsigned int pkbf(float a, float b) {
  union { __hip_bfloat162 v; unsigned int u; } c;
  c.v = __float22bfloat162_rn(make_float2(a, b));
  return c.u;
}

// ---------------- prep (one launch, fully parallel blocks): ----------------
// Round-9 verified version (best measured config).
// Unit order (longest-first so the slow scatter blocks OVERLAP the streaming
// work instead of extending the makespan tail):
// [0,32):      scatter: block hb places samples [hb*256,hb*256+256).
//              Per-wave sub-histograms (4x16: waves don't contend) +
//              wave-uniform chunk test c<hb. hb==0 publishes off_al/cnt_al
//              + zeroes xc pad row.
// [32,1824):   W1 transpose [1024][400] f32 -> [416][1024] bf16 (zero-pad)
// [1824,2720): W2 transpose [400][512] f32 -> [512][416] bf16 (zero-pad)
// [2720,3232): x convert f32 -> bf16 (16 rows/block)
__global__ __launch_bounds__(256) void prep_kernel(const float* __restrict__ W1,
                                                   const float* __restrict__ W2,
                                                   const float* __restrict__ x,
                                                   const int* __restrict__ idx,
                                                   unsigned short* __restrict__ Wt1,
                                                   unsigned short* __restrict__ Wt2,
                                                   unsigned short* __restrict__ xc,
                                                   int* __restrict__ off_al,
                                                   int* __restrict__ cnt_al,
                                                   int* __restrict__ order) {
  const int bid = blockIdx.x;
  const int t = threadIdx.x;
  if (bid < 32) {
    const int hb = bid;
    __shared__ int totW[4][E_N], preW[4][E_N];
    __shared__ int totL[E_N], preL[E_N], offsL[E_N], curL[E_N];
    const int wv = t >> 6;
    if (t < 64) { totW[t >> 4][t & 15] = 0; preW[t >> 4][t & 15] = 0; }
    __syncthreads();
#pragma unroll 1
    for (int c = 0; c < 32; ++c) {
      const int e0 = idx[c * 256 + t];
      atomicAdd(&totW[wv][e0], 1);
      if (c < hb) atomicAdd(&preW[wv][e0], 1);   // wave-uniform branch
    }
    __syncthreads();
    if (t < E_N) {
      totL[t] = totW[0][t] + totW[1][t] + totW[2][t] + totW[3][t];
      preL[t] = preW[0][t] + preW[1][t] + preW[2][t] + preW[3][t];
    }
    __syncthreads();
    if (t == 0) {
      int acc = 0;
      for (int e = 0; e < E_N; ++e) {
        offsL[e] = acc;
        if (hb == 0) off_al[e] = acc;
        acc += ((totL[e] + TM - 1) / TM) * TM;
      }
      if (hb == 0) off_al[E_N] = acc;
    }
    __syncthreads();
    if (t < E_N) {
      curL[t] = offsL[t] + preL[t];
      if (hb == 0) cnt_al[t] = totL[t];
    }
    __syncthreads();
    const int b = hb * 256 + t;
    const int e = idx[b];
    const int slot = atomicAdd(&curL[e], 1);
    order[slot] = b;
    if (hb == 0) *(uint2*)(xc + (size_t)B_N * D_K + t * 4) = make_uint2(0, 0);
  } else if (bid < 2720) {
    const int u = bid - 32;
    __shared__ unsigned short Ls[64][72];
    const float* S; unsigned short* Dt; int K, N, Kd, Nd, k0, n0;
    if (u < 1792) {                      // W1: 16 k-blocks x 7 n-blocks x 16 e
      int e = u / 112, r = u % 112;
      k0 = (r % 16) * 64; n0 = (r / 16) * 64;
      S = W1 + (size_t)e * D_K * H_N; Dt = Wt1 + (size_t)e * HP * D_K;
      K = D_K; N = H_N; Kd = D_K; Nd = HP;
    } else {                             // W2: 7 k-blocks x 8 n-blocks x 16 e
      int t2 = u - 1792; int e = t2 / 56, r = t2 % 56;
      k0 = (r % 7) * 64; n0 = (r / 7) * 64;
      S = W2 + (size_t)e * H_N * K2_N; Dt = Wt2 + (size_t)e * K2_N * HP;
      K = H_N; N = K2_N; Kd = HP; Nd = K2_N;
    }
    const int kk = t >> 4;
    const int nn = (t & 15) * 4;
    float4 v[4];
#pragma unroll
    for (int p = 0; p < 4; ++p) {
      int k = k0 + p * 16 + kk;
      int n = n0 + nn;
      v[p] = make_float4(0.f, 0.f, 0.f, 0.f);
      if (k < K && n + 3 < N) v[p] = *(const float4*)(S + (size_t)k * N + n);
    }
#pragma unroll
    for (int p = 0; p < 4; ++p) {
      Ls[nn + 0][p * 16 + kk] = f2bf(v[p].x);
      Ls[nn + 1][p * 16 + kk] = f2bf(v[p].y);
      Ls[nn + 2][p * 16 + kk] = f2bf(v[p].z);
      Ls[nn + 3][p * 16 + kk] = f2bf(v[p].w);
    }
    __syncthreads();
    const int n2 = t >> 3;
    const int ch = t & 7;
#pragma unroll
    for (int p = 0; p < 2; ++p) {
      int n = n0 + p * 32 + n2;
      int k = k0 + ch * 8;
      if (n < Nd && k < Kd)
        *(uint4*)(Dt + (size_t)n * Kd + k) = *(const uint4*)&Ls[p * 32 + n2][ch * 8];
    }
  } else {
    const int xb = bid - 2720;
    const float* S = x + (size_t)xb * 16 * D_K;
    unsigned short* Dp = xc + (size_t)xb * 16 * D_K;
#pragma unroll
    for (int i = 0; i < 16; ++i) {
      float4 v = *(const float4*)(S + i * D_K + t * 4);
      uint2 o; o.x = pkbf(v.x, v.y); o.y = pkbf(v.z, v.w);
      *(uint2*)(Dp + i * D_K + t * 4) = o;
    }
  }
}

// XCD-clustering swizzle for the GEMM grids (576 wgs, 8 XCDs, 72/XCD):
// linear dispatch id L -> vid = (L%8)*72 + L/8 (bijective), decode
// mt = vid>>2 (m-tile), nb = vid&3 (n-chunk).
static __device__ __forceinline__ void swz_decode(int bx, int by, int& mt, int& nb) {
  const int L = bx + NTILES * by;          // 0..575
  const int vid = (L & 7) * 72 + (L >> 3);
  mt = vid >> 2;
  nb = vid & 3;
}

// ---------------- GEMM1: R9 structure + BALANCED tile map -------------------
// Round-11 change (only): tile->slot map t0=8nb+2w packed tiles 24.. into
// chunk nb=3, leaving those 144 blocks with 1/8 active slots (waves 1-3 did
// zero MFMA for the whole K loop) while nb=0-2 blocks carried 8. New map:
// tileA = nb + 8w, tileB = tileA + 4 (bijective onto 0..24; act1 implies
// act0). Active slots/block: {8,8,8,1} -> {7,6,6,6}: max per-CU work -12.5%,
// no near-no-op blocks. A-staging (unconditional, all 64 rows) unchanged;
// everything else byte-exact round-9/R2 config.
__global__ __launch_bounds__(256) void gemm1_kernel(const unsigned short* __restrict__ xc,
                                                    const unsigned short* __restrict__ Wt1,
                                                    const float* __restrict__ b1,
                                                    const int* __restrict__ off_al,
                                                    const int* __restrict__ cnt_al,
                                                    const int* __restrict__ order,
                                                    unsigned short* __restrict__ h1buf) {
  __shared__ unsigned short As[2 * 2 * 2048];   // [buf][ksub][64*32]  16 KB
  __shared__ unsigned short Bs[2 * 2 * 4096];   // [buf][ksub][128*32] 32 KB
  __shared__ int offs[E_N + 1];
  __shared__ int rowidx[TM];
  const int tid = threadIdx.x;
  int mt, nb;
  swz_decode(blockIdx.x, blockIdx.y, mt, nb);
  const int m0 = mt * TM;
  if (tid <= E_N) offs[tid] = off_al[tid];
  __syncthreads();
  if (m0 >= offs[E_N]) return;
  int e = 0;
  while (m0 >= offs[e + 1]) ++e;
  if (tid < TM) {
    const bool valid = (m0 + tid) < (offs[e] + cnt_al[e]);
    rowidx[tid] = valid ? order[m0 + tid] : B_N;   // pad -> zero row
  }
  __syncthreads();
  const unsigned short* Wt1e = Wt1 + (size_t)e * HP * D_K;

  const int l = tid & 63, w = tid >> 6;
  const int r4 = l >> 2;
  const int sg = (r4 ^ (r4 >> 2)) & 3;
  const int g8 = ((l & 3) ^ sg) * 8;
  const int tA = nb + 8 * w;                // balanced map: wave's two tiles
  const int tB = tA + 4;                    // are 4 apart (64 cols)
  const bool act0 = (tA < 25);
  const bool act1 = (tB < 25);              // act1 => act0
  const unsigned short* gA = xc + (size_t)rowidx[16 * w + r4] * D_K + g8;
  const unsigned short* gB0 = Wt1e + (size_t)(tA * 16 + r4) * D_K + g8;
  const unsigned short* gB1 = Wt1e + (size_t)(tB * 16 + r4) * D_K + g8;

  const int ln = l & 15, q = l >> 4;
  const int sr = (ln ^ (ln >> 2)) & 3;
  const int cq = (q ^ sr) * 8;

  f32x4 acc[4][2] = {};

  // prologue: stage K 0..63 (both 32-wide halves) into buf 0
#pragma unroll
  for (int ks = 0; ks < 2; ++ks) {
    GLDS(gA + ks * 32, &As[ks * 2048 + 16 * w * 32]);
    if (act0) GLDS(gB0 + ks * 32, &Bs[ks * 4096 + (2 * w + 0) * 512]);
    if (act1) GLDS(gB1 + ks * 32, &Bs[ks * 4096 + (2 * w + 1) * 512]);
  }

  for (int k0 = 0; k0 < D_K; k0 += 64) {    // 16 iterations
    const int cur = (k0 >> 6) & 1;
    const int nxt = cur ^ 1;
    __syncthreads();               // publishes buf[cur] (implicit vmcnt(0))
    if (k0 + 64 < D_K) {
#pragma unroll
      for (int ks = 0; ks < 2; ++ks) {
        const int kg = k0 + 64 + ks * 32;
        GLDS(gA + kg, &As[nxt * 4096 + ks * 2048 + 16 * w * 32]);
        if (act0) GLDS(gB0 + kg, &Bs[nxt * 8192 + ks * 4096 + (2 * w + 0) * 512]);
        if (act1) GLDS(gB1 + kg, &Bs[nxt * 8192 + ks * 4096 + (2 * w + 1) * 512]);
      }
    }
    if (act0) {
#pragma unroll
      for (int ks = 0; ks < 2; ++ks) {
        const unsigned short* Ab = &As[cur * 4096 + ks * 2048];
        const unsigned short* Bb = &Bs[cur * 8192 + ks * 4096];
        bf16x8 af[4];
#pragma unroll
        for (int i = 0; i < 4; ++i)
          af[i] = *(const bf16x8*)&Ab[(16 * i + ln) * 32 + cq];
        bf16x8 b0f = *(const bf16x8*)&Bb[(2 * w + 0) * 512 + ln * 32 + cq];
#pragma unroll
        for (int i = 0; i < 4; ++i)
          acc[i][0] = __builtin_amdgcn_mfma_f32_16x16x32_bf16(b0f, af[i], acc[i][0], 0, 0, 0);
        if (act1) {
          bf16x8 b1f = *(const bf16x8*)&Bb[(2 * w + 1) * 512 + ln * 32 + cq];
#pragma unroll
          for (int i = 0; i < 4; ++i)
            acc[i][1] = __builtin_amdgcn_mfma_f32_16x16x32_bf16(b1f, af[i], acc[i][1], 0, 0, 0);
        }
      }
    }
  }

  // swapped layout: lane holds m = m0+16i+ln (col=lane&15), n = tile*16+4q+reg.
#pragma unroll
  for (int j = 0; j < 2; ++j) {
    if (j == 0 ? act0 : act1) {
      const int n4 = (j == 0 ? tA : tB) * 16 + 4 * q;   // always < 400
      const float4 bv = *(const float4*)&b1[e * H_N + n4];
#pragma unroll
      for (int i = 0; i < 4; ++i) {
        const size_t m = (size_t)(m0 + 16 * i + ln);
        uint2 o;
        o.x = pkbf(fmaxf(acc[i][j][0] + bv.x, 0.f), fmaxf(acc[i][j][1] + bv.y, 0.f));
        o.y = pkbf(fmaxf(acc[i][j][2] + bv.z, 0.f), fmaxf(acc[i][j][3] + bv.w, 0.f));
        *(uint2*)&h1buf[m * HP + n4] = o;
      }
    }
  }
  // h1 pad cols [400,416) stay unwritten: Wt2 rows there are zero.
}

// ---------------- GEMM2 (byte-exact best-measured R2 config) ----------------
// grid (144,4) swizzled; two 16-col tiles/wave; BK=64 double-sub-tile K-step.
// K=416 -> 7 iterations, last does only the low 32-wide half. 32 tiles exact
// -> already perfectly balanced; unchanged.
__global__ __launch_bounds__(256) void gemm2_kernel(const unsigned short* __restrict__ h1buf,
                                                    const unsigned short* __restrict__ Wt2,
                                                    const float* __restrict__ b2,
                                                    const int* __restrict__ off_al,
                                                    const int* __restrict__ cnt_al,
                                                    const int* __restrict__ order,
                                                    float* __restrict__ out) {
  __shared__ unsigned short As[2 * 2 * 2048];
  __shared__ unsigned short Bs[2 * 2 * 4096];
  __shared__ int offs[E_N + 1];
  __shared__ int rowidx[TM];
  const int tid = threadIdx.x;
  int mt, nb;
  swz_decode(blockIdx.x, blockIdx.y, mt, nb);
  const int m0 = mt * TM;
  if (tid <= E_N) offs[tid] = off_al[tid];
  __syncthreads();
  if (m0 >= offs[E_N]) return;
  int e = 0;
  while (m0 >= offs[e + 1]) ++e;
  if (tid < TM) {
    const bool valid = (m0 + tid) < (offs[e] + cnt_al[e]);
    rowidx[tid] = valid ? order[m0 + tid] : -1;
  }
  __syncthreads();
  const unsigned short* Wt2e = Wt2 + (size_t)e * K2_N * HP;

  const int l = tid & 63, w = tid >> 6;
  const int r4 = l >> 2;
  const int sg = (r4 ^ (r4 >> 2)) & 3;
  const int g8 = ((l & 3) ^ sg) * 8;
  const int t0 = nb * 8 + 2 * w;            // two 16-col tiles of 32 (exact)
  const unsigned short* gA = h1buf + (size_t)(m0 + 16 * w + r4) * HP + g8;
  const unsigned short* gB0 = Wt2e + (size_t)(t0 * 16 + r4) * HP + g8;
  const unsigned short* gB1 = gB0 + (size_t)16 * HP;

  const int ln = l & 15, q = l >> 4;
  const int sr = (ln ^ (ln >> 2)) & 3;
  const int cq = (q ^ sr) * 8;

  f32x4 acc[4][2] = {};

  // prologue: stage K 0..63 into buf 0
#pragma unroll
  for (int ks = 0; ks < 2; ++ks) {
    GLDS(gA + ks * 32, &As[ks * 2048 + 16 * w * 32]);
    GLDS(gB0 + ks * 32, &Bs[ks * 4096 + (2 * w + 0) * 512]);
    GLDS(gB1 + ks * 32, &Bs[ks * 4096 + (2 * w + 1) * 512]);
  }

  for (int k0 = 0; k0 < HP; k0 += 64) {     // 7 iterations (last = half)
    const int cur = (k0 >> 6) & 1;
    const int nxt = cur ^ 1;
    __syncthreads();
#pragma unroll
    for (int ks = 0; ks < 2; ++ks) {
      const int kg = k0 + 64 + ks * 32;
      if (kg < HP) {
        GLDS(gA + kg, &As[nxt * 4096 + ks * 2048 + 16 * w * 32]);
        GLDS(gB0 + kg, &Bs[nxt * 8192 + ks * 4096 + (2 * w + 0) * 512]);
        GLDS(gB1 + kg, &Bs[nxt * 8192 + ks * 4096 + (2 * w + 1) * 512]);
      }
    }
#pragma unroll
    for (int ks = 0; ks < 2; ++ks) {
      if (k0 + ks * 32 < HP) {
        const unsigned short* Ab = &As[cur * 4096 + ks * 2048];
        const unsigned short* Bb = &Bs[cur * 8192 + ks * 4096];
        bf16x8 af[4];
#pragma unroll
        for (int i = 0; i < 4; ++i)
          af[i] = *(const bf16x8*)&Ab[(16 * i + ln) * 32 + cq];
        bf16x8 b0f = *(const bf16x8*)&Bb[(2 * w + 0) * 512 + ln * 32 + cq];
#pragma unroll
        for (int i = 0; i < 4; ++i)
          acc[i][0] = __builtin_amdgcn_mfma_f32_16x16x32_bf16(b0f, af[i], acc[i][0], 0, 0, 0);
        bf16x8 b1f = *(const bf16x8*)&Bb[(2 * w + 1) * 512 + ln * 32 + cq];
#pragma unroll
        for (int i = 0; i < 4; ++i)
          acc[i][1] = __builtin_amdgcn_mfma_f32_16x16x32_bf16(b1f, af[i], acc[i][1], 0, 0, 0);
      }
    }
  }

  // swapped layout: lane holds m = m0+16i+ln, n = tile*16+4q+reg (4 consecutive).
#pragma unroll
  for (int j = 0; j < 2; ++j) {
    const int n4 = (t0 + j) * 16 + 4 * q;
    const float4 bv = *(const float4*)&b2[e * K2_N + n4];
#pragma unroll
    for (int i = 0; i < 4; ++i) {
      const int s = rowidx[16 * i + ln];
      if (s >= 0) {
        float4 v;
        v.x = acc[i][j][0] + bv.x;
        v.y = acc[i][j][1] + bv.y;
        v.z = acc[i][j][2] + bv.z;
        v.w = acc[i][j][3] + bv.w;
        if (n4 < L_N) *(float4*)&out[(size_t)s * L_N + n4] = v;
        else          *(float4*)&out[(size_t)(B_N + s) * L_N + (n4 - L_N)] = v;
      }
    }
  }
}

extern "C" void kernel_launch(void* const* d_in, const int* in_sizes, int n_in,
                              void* d_out, int out_size, void* d_ws, size_t ws_size,
                              hipStream_t stream) {
  const float* x   = (const float*)d_in[0];
  const int*   idx = (const int*)d_in[1];
  const float* W1  = (const float*)d_in[2];
  const float* b1  = (const float*)d_in[3];
  const float* W2  = (const float*)d_in[4];
  const float* b2  = (const float*)d_in[5];
  float* out = (float*)d_out;

  // ws layout (bytes), total ~44.9 MB:
  // off_al@0 (68) | cnt_al@128 (64) | order@2240 (36864)
  // xc@39104 ((8192+1)x1024x2) | h1@16,818,368 (9216x416x2)
  // Wt1@24,486,080 (16x416x1024x2) | Wt2@38,117,568 (16x512x416x2)
  char* ws = (char*)d_ws;
  int* off_al = (int*)(ws + 0);
  int* cnt_al = (int*)(ws + 128);
  int* order  = (int*)(ws + 2240);
  unsigned short* xc  = (unsigned short*)(ws + 39104);
  unsigned short* h1  = (unsigned short*)(ws + 16818368);
  unsigned short* Wt1 = (unsigned short*)(ws + 24486080);
  unsigned short* Wt2 = (unsigned short*)(ws + 38117568);

  prep_kernel<<<3232, 256, 0, stream>>>(W1, W2, x, idx, Wt1, Wt2, xc,
                                        off_al, cnt_al, order);
  gemm1_kernel<<<dim3(NTILES, 4), 256, 0, stream>>>(xc, Wt1, b1, off_al, cnt_al, order, h1);
  gemm2_kernel<<<dim3(NTILES, 4), 256, 0, stream>>>(h1, Wt2, b2, off_al, cnt_al, order, out);
}